// Round 3
// baseline (1191.022 us; speedup 1.0000x reference)
//
#include <hip/hip_runtime.h>

// Seq2Seq LSTM (enc 512 + dec 256 steps), H=50, B=2048, in/out dim 1.
//
// Round-3: back to 1 wave = 1 batch element (round-1 frame, lowest overhead),
// with two fixes for the AGPR copy storm diagnosed in rounds 1-2:
//  * __launch_bounds__(64,1): unified VGPR budget 512/wave, so ~230 live
//    floats fit in ARCH VGPRs (<=256). gfx950 VALU cannot read AGPRs as
//    operands, so AGPR-resident weights cost a v_accvgpr_read per use --
//    that was ~2x of rounds 1-2. Runtime occupancy still 2 waves/SIMD
//    (512-reg pool / ~240 regs).
//  * Packed fp32: v_pk_fma_f32 via <2 x float> elementwise fma -> 204 scalar
//    FMAs become 100 packed ones. Exact fp32 semantics.
//
// Lane j owns hidden unit j (lanes 50-63 clamp to 49, never write). Weights
// as 25 float2 per gate (200 VGPRs). h exchanged via double-buffered LDS,
// read back as broadcast float4 (conflict-free); 1 barrier/step (cheap in a
// single-wave block). Decoder y from full shfl_xor butterfly (all lanes).

#define HID 50
#define SEQ 512
#define TGT 256

typedef float v2f __attribute__((ext_vector_type(2)));

__device__ __forceinline__ float sigm(float x) {
    return 1.0f / (1.0f + __expf(-x));            // +-inf safe
}
__device__ __forceinline__ float tanh_(float x) {
    return 2.0f / (1.0f + __expf(-2.0f * x)) - 1.0f;
}

// Load this lane's 4 gate rows of W_hh as float2 pairs (+ wx scalar, bias).
#define LOAD_W(Wih, Whh, Bih, Bhh)                                    \
    {                                                                 \
        _Pragma("unroll")                                             \
        for (int g = 0; g < 4; ++g) {                                 \
            const v2f* r2 = (const v2f*)((Whh) + (size_t)(g * HID + u) * HID); \
            _Pragma("unroll")                                         \
            for (int p = 0; p < 25; ++p) wp[g][p] = r2[p];            \
            wx[g] = (Wih)[g * HID + u];                               \
            bb[g] = (Bih)[g * HID + u] + (Bhh)[g * HID + u];          \
        }                                                             \
    }

// One LSTM step. acc_g starts as {bb_g, wx_g*x}; 12 float4 broadcast reads
// feed 2 pk_fma each; pair 24 (k=48,49) read as float2. Defines hn, updates c.
#define STEP_GATES(xv, hb)                                            \
    v2f ac0 = {bb[0], wx[0] * (xv)};                                  \
    v2f ac1 = {bb[1], wx[1] * (xv)};                                  \
    v2f ac2 = {bb[2], wx[2] * (xv)};                                  \
    v2f ac3 = {bb[3], wx[3] * (xv)};                                  \
    {                                                                 \
        const float4* h4 = (const float4*)(hb);                      \
        _Pragma("unroll")                                             \
        for (int q = 0; q < 12; ++q) {                                \
            float4 hv = h4[q];                                        \
            v2f hxy = {hv.x, hv.y};                                   \
            v2f hzw = {hv.z, hv.w};                                   \
            ac0 = __builtin_elementwise_fma(wp[0][2 * q], hxy, ac0);  \
            ac1 = __builtin_elementwise_fma(wp[1][2 * q], hxy, ac1);  \
            ac2 = __builtin_elementwise_fma(wp[2][2 * q], hxy, ac2);  \
            ac3 = __builtin_elementwise_fma(wp[3][2 * q], hxy, ac3);  \
            ac0 = __builtin_elementwise_fma(wp[0][2 * q + 1], hzw, ac0); \
            ac1 = __builtin_elementwise_fma(wp[1][2 * q + 1], hzw, ac1); \
            ac2 = __builtin_elementwise_fma(wp[2][2 * q + 1], hzw, ac2); \
            ac3 = __builtin_elementwise_fma(wp[3][2 * q + 1], hzw, ac3); \
        }                                                             \
        v2f ht = ((const v2f*)(hb))[24];  /* k = 48,49 */             \
        ac0 = __builtin_elementwise_fma(wp[0][24], ht, ac0);          \
        ac1 = __builtin_elementwise_fma(wp[1][24], ht, ac1);          \
        ac2 = __builtin_elementwise_fma(wp[2][24], ht, ac2);          \
        ac3 = __builtin_elementwise_fma(wp[3][24], ht, ac3);          \
    }                                                                 \
    float gi = sigm(ac0.x + ac0.y);                                   \
    float gf = sigm(ac1.x + ac1.y);                                   \
    float gg = tanh_(ac2.x + ac2.y);                                  \
    float go = sigm(ac3.x + ac3.y);                                   \
    c = fmaf(gf, c, gi * gg);                                         \
    float hn = go * tanh_(c);

extern "C" __global__ void __launch_bounds__(64, 1)
seq2seq_kernel(const float* __restrict__ src,
               const float* __restrict__ eWih, const float* __restrict__ eWhh,
               const float* __restrict__ eBih, const float* __restrict__ eBhh,
               const float* __restrict__ dWih, const float* __restrict__ dWhh,
               const float* __restrict__ dBih, const float* __restrict__ dBhh,
               const float* __restrict__ fcW, const float* __restrict__ fcB,
               float* __restrict__ out) {
    const int b = blockIdx.x;
    const int j = threadIdx.x;                  // lane 0..63
    const int u = (j < HID) ? j : (HID - 1);    // clamp: lanes 50-63 mirror 49
    const bool act = (j < HID);

    __shared__ float hbuf[2][64];               // double-buffered h state
    hbuf[0][j] = 0.0f;
    hbuf[1][j] = 0.0f;
    __syncthreads();

    v2f wp[4][25];                              // 200 weight VGPRs
    float wx[4], bb[4];
    float c = 0.0f;
    int cur = 0;

    // ---------------- encoder: 512 steps ----------------
    LOAD_W(eWih, eWhh, eBih, eBhh);
    const float* sb = src + (size_t)b * SEQ;
    float x = sb[0];
    for (int t = 0; t < SEQ; ++t) {
        float xn = sb[(t + 1 < SEQ) ? (t + 1) : 0];   // prefetch next x
        STEP_GATES(x, hbuf[cur])
        if (act) hbuf[cur ^ 1][u] = hn;               // write other buffer
        __syncthreads();                              // 1 barrier (1-wave blk)
        cur ^= 1;
        x = xn;
    }

    // ---------------- decoder: 256 steps ----------------
    LOAD_W(dWih, dWhh, dBih, dBhh);
    const float fw = act ? fcW[u] : 0.0f;
    const float fb = fcB[0];
    float* ob = out + (size_t)b * TGT;

    x = 0.0f;                                         // decoder_input = zeros
    for (int t = 0; t < TGT; ++t) {
        STEP_GATES(x, hbuf[cur])
        float p = fw * hn;                            // fc dot via butterfly
#pragma unroll
        for (int off = 32; off > 0; off >>= 1) p += __shfl_xor(p, off, 64);
        float y = p + fb;                             // every lane has y
        if (j == 0) ob[t] = y;
        if (act) hbuf[cur ^ 1][u] = hn;
        __syncthreads();
        cur ^= 1;
        x = y;                                        // feed back as input
    }
}

extern "C" void kernel_launch(void* const* d_in, const int* in_sizes, int n_in,
                              void* d_out, int out_size, void* d_ws, size_t ws_size,
                              hipStream_t stream) {
    const float* src  = (const float*)d_in[0];
    const float* eWih = (const float*)d_in[1];
    const float* eWhh = (const float*)d_in[2];
    const float* eBih = (const float*)d_in[3];
    const float* eBhh = (const float*)d_in[4];
    const float* dWih = (const float*)d_in[5];
    const float* dWhh = (const float*)d_in[6];
    const float* dBih = (const float*)d_in[7];
    const float* dBhh = (const float*)d_in[8];
    const float* fcW  = (const float*)d_in[9];
    const float* fcB  = (const float*)d_in[10];
    float* out = (float*)d_out;

    const int B = in_sizes[0] / SEQ;     // 2048
    seq2seq_kernel<<<B, 64, 0, stream>>>(src, eWih, eWhh, eBih, eBhh,
                                         dWih, dWhh, dBih, dBhh, fcW, fcB, out);
}

// Round 4
// 1123.189 us; speedup vs baseline: 1.0604x; 1.0604x over previous
//
#include <hip/hip_runtime.h>

// Seq2Seq LSTM (enc 512 + dec 256 steps), H=50, B=2048, in/out dim 1.
//
// Round-4: defeat the register allocator by construction. Rounds 1-3 all
// needed >=100 live weight floats/lane and LLVM parked them in AGPRs
// (gfx950 VALU cannot read AGPR operands -> v_accvgpr_read per use) plus
// scratch spills (GBs of FETCH_SIZE). Fix: 4 waves per batch element,
// wave g owns gate g (PyTorch order i,f,g,o): lane j holds only
// W_hh[g*50+j][0:50] = 50 regs (25 v2f for v_pk_fma_f32) -> ~80 live regs,
// far below every allocation cliff -> clean arch-VGPR codegen + ~6 waves/SIMD.
//
// Per step: each wave dots its gate vs h (from its OWN per-wave LDS h copy,
// broadcast reads), applies its gate's nonlinearity, writes 1 float to an
// interleaved gate buffer; ONE barrier; every wave reads float4 {i,f,g,o},
// redundantly updates replicated c and h[j], writes h to its own h buffer
// (same-wave DS ordering makes a second barrier unnecessary; gbuf is
// double-buffered so one barrier/step is sufficient).
// Decoder y = fc(h) via redundant per-wave shfl butterfly (no extra sync).

#define HID 50
#define SEQ 512
#define TGT 256

typedef float v2f __attribute__((ext_vector_type(2)));

__device__ __forceinline__ float sigm(float x) {
    return 1.0f / (1.0f + __expf(-x));            // +-inf safe
}
__device__ __forceinline__ float tanh_(float x) {
    return 2.0f / (1.0f + __expf(-2.0f * x)) - 1.0f;
}

// Load this lane's single gate row (25 v2f) + wx scalar + summed bias.
// Row byte offset = (g*50+u)*200 bytes -> always 8B aligned (v2f ok).
#define LOAD_W(Wih, Whh, Bih, Bhh)                                    \
    {                                                                 \
        const v2f* r2 = (const v2f*)((Whh) + (size_t)(g * HID + u) * HID); \
        _Pragma("unroll")                                             \
        for (int p = 0; p < 25; ++p) wp[p] = r2[p];                   \
        wx = (Wih)[g * HID + u];                                      \
        bb = (Bih)[g * HID + u] + (Bhh)[g * HID + u];                 \
    }

// One step: gate dot + activation -> gbuf; barrier; gather 4 gates ->
// update replicated c, h; write h to own hbuf. Defines hn.
#define STEP(xv)                                                      \
    v2f ac = {bb, wx * (xv)};                                         \
    {                                                                 \
        const v2f* h2 = (const v2f*)hbuf[g][cur];                     \
        _Pragma("unroll")                                             \
        for (int p = 0; p < 25; ++p)                                  \
            ac = __builtin_elementwise_fma(wp[p], h2[p], ac);         \
    }                                                                 \
    {                                                                 \
        float a = ac.x + ac.y;                                        \
        float v = (g == 2) ? tanh_(a) : sigm(a);                      \
        if (act) gbuf[cur][j][g] = v;                                 \
    }                                                                 \
    __syncthreads();                                                  \
    float hn;                                                         \
    {                                                                 \
        float4 gv = *(const float4*)gbuf[cur][jr];  /* i,f,g,o */     \
        c = fmaf(gv.y, c, gv.x * gv.z);                               \
        hn = gv.w * tanh_(c);                                         \
        hbuf[g][cur ^ 1][j] = hn;   /* own buffer; lanes 50-63 write  \
                                       slots never read (reads k<50) */\
    }                                                                 \
    cur ^= 1;

extern "C" __global__ void __launch_bounds__(256)
seq2seq_kernel(const float* __restrict__ src,
               const float* __restrict__ eWih, const float* __restrict__ eWhh,
               const float* __restrict__ eBih, const float* __restrict__ eBhh,
               const float* __restrict__ dWih, const float* __restrict__ dWhh,
               const float* __restrict__ dBih, const float* __restrict__ dBhh,
               const float* __restrict__ fcW, const float* __restrict__ fcB,
               float* __restrict__ out) {
    const int b   = blockIdx.x;
    const int tid = threadIdx.x;          // 0..255
    const int g   = tid >> 6;             // wave id = gate id (i,f,g,o)
    const int j   = tid & 63;             // lane
    const bool act = (j < HID);
    const int u   = act ? j : (HID - 1);  // clamped unit id (weight loads)
    const int jr  = act ? j : (HID - 1);  // clamped gbuf read index

    __shared__ float hbuf[4][2][64];      // per-wave h copies, double-buffered
    __shared__ float gbuf[2][64][4];      // activated gates, interleaved

    hbuf[g][0][j] = 0.0f;                 // own-wave init; in-order DS makes
                                          // step-0 reads safe without barrier
    float c = 0.0f;
    int cur = 0;

    v2f wp[25];                           // 50 weight VGPRs -- the whole point
    float wx, bb;

    // ---------------- encoder: 512 steps ----------------
    LOAD_W(eWih, eWhh, eBih, eBhh);
    const float* sb = src + (size_t)b * SEQ;
    float x = sb[0];
    for (int t = 0; t < SEQ; ++t) {
        float xn = sb[(t + 1 < SEQ) ? (t + 1) : 0];   // prefetch next x
        STEP(x)
        x = xn;
    }

    // ---------------- decoder: 256 steps ----------------
    LOAD_W(dWih, dWhh, dBih, dBhh);
    const float fw = act ? fcW[u] : 0.0f; // lanes 50-63 must contribute 0
    const float fb = fcB[0];
    float* ob = out + (size_t)b * TGT;

    x = 0.0f;                             // decoder_input = zeros
    for (int t = 0; t < TGT; ++t) {
        STEP(x)
        float p = fw * hn;                // every wave reduces redundantly
#pragma unroll
        for (int off = 32; off > 0; off >>= 1) p += __shfl_xor(p, off, 64);
        float y = p + fb;
        if (tid == 0) ob[t] = y;
        x = y;                            // feed back as next input
    }
}

extern "C" void kernel_launch(void* const* d_in, const int* in_sizes, int n_in,
                              void* d_out, int out_size, void* d_ws, size_t ws_size,
                              hipStream_t stream) {
    const float* src  = (const float*)d_in[0];
    const float* eWih = (const float*)d_in[1];
    const float* eWhh = (const float*)d_in[2];
    const float* eBih = (const float*)d_in[3];
    const float* eBhh = (const float*)d_in[4];
    const float* dWih = (const float*)d_in[5];
    const float* dWhh = (const float*)d_in[6];
    const float* dBih = (const float*)d_in[7];
    const float* dBhh = (const float*)d_in[8];
    const float* fcW  = (const float*)d_in[9];
    const float* fcB  = (const float*)d_in[10];
    float* out = (float*)d_out;

    const int B = in_sizes[0] / SEQ;      // 2048
    seq2seq_kernel<<<B, 256, 0, stream>>>(src, eWih, eWhh, eBih, eBhh,
                                          dWih, dWhh, dBih, dBhh, fcW, fcB, out);
}

// Round 5
// 1078.634 us; speedup vs baseline: 1.1042x; 1.0413x over previous
//
#include <hip/hip_runtime.h>

// Seq2Seq LSTM (enc 512 + dec 256 steps), H=50, B=2048, in/out dim 1.
//
// Round-5: r4 was LDS-pipe-bound (~112 DS instr/element-step: 4 waves each
// re-reading all 50 h values + 8-way-conflicted gbuf). New decomposition:
// block 256 thr = 1 element; QUAD q owns hidden unit u=q (u<50). Within a
// quad, lane qi = 2*gp + kh: gate-pair gp0={i,f} gp1={g,o}, k-half kh
// (k in [0,28) / [28,56), h padded to 56 with zeros). Per lane: 2 gate rows
// x 28 k = 56 weight VGPRs (safely under the ~128 AGPR-split cliff proven
// in r1-r3). Cross-lane combines use DPP quad_perm (pure VALU, no LDS):
//  - k-half partial sum: 1 dpp_xor1
//  - activation: lane qi activates gate qi once, via unified a*sigm(b*x)+g
//  - quad gather of {i,f,g,o}: dpp_xor1 + dpp_xor2 + cndmask selects
// h exchanged via ONE shared double-buffered LDS buffer, 1 barrier/step;
// DS per wave-step = 7 broadcast ds_read_b128 + 1 write (vs r4's ~27).
// Decoder fc: per-wave butterfly -> pbuf, folded into the same barrier.

#define HID 50
#define SEQ 512
#define TGT 256
#define KH  28      // padded k-half length (k-half1 holds 22 real + 6 zeros)

typedef float v2f __attribute__((ext_vector_type(2)));

#define XOR1 0xB1   // quad_perm [1,0,3,2]
#define XOR2 0x4E   // quad_perm [2,3,0,1]

template <int CTRL>
__device__ __forceinline__ float dpp_perm(float x) {
    return __int_as_float(__builtin_amdgcn_update_dpp(
        0, __float_as_int(x), CTRL, 0xF, 0xF, true));
}

// Load this lane's 2 gate rows (k-half, zero-padded) + its OWN gate's (qi)
// wx scalar and summed bias.
#define LOAD_W(Wih, Whh, Bih, Bhh)                                     \
    {                                                                  \
        const float* r0 = (Whh) + (size_t)((2 * gp) * HID + u) * HID;  \
        const float* r1 = (Whh) + (size_t)((2 * gp + 1) * HID + u) * HID; \
        _Pragma("unroll")                                              \
        for (int p = 0; p < 14; ++p) {                                 \
            int k = k0 + 2 * p;                                        \
            float a0 = (k < HID)     ? r0[k]     : 0.0f;               \
            float b0 = (k + 1 < HID) ? r0[k + 1] : 0.0f;               \
            float a1 = (k < HID)     ? r1[k]     : 0.0f;               \
            float b1 = (k + 1 < HID) ? r1[k + 1] : 0.0f;               \
            wg0[p] = (v2f){a0, b0};                                    \
            wg1[p] = (v2f){a1, b1};                                    \
        }                                                              \
        wx = (Wih)[qi * HID + u];                                      \
        bb = (Bih)[qi * HID + u] + (Bhh)[qi * HID + u];                \
    }

// One LSTM step (no barrier inside). Defines hn; updates c.
#define STEP(xv)                                                       \
    v2f ac0 = {0.f, 0.f}, ac1 = {0.f, 0.f};                            \
    {                                                                  \
        const float4* h4 = (const float4*)(hbuf[cur] + k0);            \
        _Pragma("unroll")                                              \
        for (int q = 0; q < 7; ++q) {                                  \
            float4 hv = h4[q];                                         \
            v2f ha = {hv.x, hv.y};                                     \
            v2f hb = {hv.z, hv.w};                                     \
            ac0 = __builtin_elementwise_fma(wg0[2 * q],     ha, ac0);  \
            ac1 = __builtin_elementwise_fma(wg1[2 * q],     ha, ac1);  \
            ac0 = __builtin_elementwise_fma(wg0[2 * q + 1], hb, ac0);  \
            ac1 = __builtin_elementwise_fma(wg1[2 * q + 1], hb, ac1);  \
        }                                                              \
    }                                                                  \
    float t0 = ac0.x + ac0.y, t1 = ac1.x + ac1.y;                      \
    float tm = kh ? t1 : t0;   /* my gate's partial  */                \
    float tn = kh ? t0 : t1;   /* partner-gate partial I hold */       \
    float a  = tm + dpp_perm<XOR1>(tn);  /* full 56-k dot for gate qi */ \
    a = fmaf(wx, (xv), a + bb);                                        \
    /* unified activation: sigm for i,f,o; tanh = 2*sigm(2a)-1 for g */ \
    float act = fmaf(alpha, 1.0f / (1.0f + __expf(-beta * a)), gam);   \
    /* quad gather of the 4 activated gates via DPP */                 \
    float B_ = dpp_perm<XOR1>(act);                                    \
    float first  = kh ? B_ : act;   /* i (gp0) or g (gp1) */           \
    float second = kh ? act : B_;   /* f (gp0) or o (gp1) */           \
    float C_ = dpp_perm<XOR2>(first);                                  \
    float D_ = dpp_perm<XOR2>(second);                                 \
    float gi = gp ? C_ : first;                                        \
    float gg = gp ? first : C_;                                        \
    float gf = gp ? D_ : second;                                       \
    float go = gp ? second : D_;                                       \
    c = fmaf(gf, c, gi * gg);                                          \
    float hn = go * fmaf(2.0f, 1.0f / (1.0f + __expf(-2.0f * c)), -1.0f); \
    if (wr) hbuf[cur ^ 1][Q] = hn;   /* pads [50..55] stay 0 */

extern "C" __global__ void __launch_bounds__(256, 2)
seq2seq_kernel(const float* __restrict__ src,
               const float* __restrict__ eWih, const float* __restrict__ eWhh,
               const float* __restrict__ eBih, const float* __restrict__ eBhh,
               const float* __restrict__ dWih, const float* __restrict__ dWhh,
               const float* __restrict__ dBih, const float* __restrict__ dBhh,
               const float* __restrict__ fcW, const float* __restrict__ fcB,
               float* __restrict__ out) {
    const int b    = blockIdx.x;
    const int tid  = threadIdx.x;        // 0..255
    const int lane = tid & 63;
    const int w    = tid >> 6;           // wave 0..3
    const int Q    = tid >> 2;           // quad id = unit id (0..63)
    const int qi   = tid & 3;            // role within quad = my gate
    const int gp   = qi >> 1;            // gate pair: 0={i,f} 1={g,o}
    const int kh   = qi & 1;             // k-half
    const int k0   = kh * KH;            // 0 or 28 (float4-aligned: 112 B)
    const bool actQ = (Q < HID);
    const int u    = actQ ? Q : (HID - 1);
    const bool wr  = (qi == 0) && actQ;  // h writer / fc contributor

    __shared__ __align__(16) float hbuf[2][56];  // padded h, double-buffered
    __shared__ __align__(16) float pbuf[2][4];   // decoder fc wave partials

    if (tid < 56) { hbuf[0][tid] = 0.0f; hbuf[1][tid] = 0.0f; }
    if (tid < 8)  ((float*)pbuf)[tid] = 0.0f;
    __syncthreads();

    // per-lane unified-activation constants (gate g=2 is tanh)
    const float alpha = (qi == 2) ? 2.0f : 1.0f;
    const float beta  = alpha;
    const float gam   = (qi == 2) ? -1.0f : 0.0f;

    v2f wg0[14], wg1[14];                // 56 weight VGPRs
    float wx, bb;
    float c = 0.0f;
    int cur = 0;

    // ---------------- encoder: 512 steps ----------------
    LOAD_W(eWih, eWhh, eBih, eBhh);
    const float* sb = src + (size_t)b * SEQ;
    float x = sb[0];
    for (int t = 0; t < SEQ; ++t) {
        float xn = sb[(t + 1 < SEQ) ? (t + 1) : 0];   // prefetch next x
        STEP(x)
        __syncthreads();                 // h(cur^1) now visible to all waves
        cur ^= 1;
        x = xn;
    }

    // ---------------- decoder: 256 steps ----------------
    LOAD_W(dWih, dWhh, dBih, dBhh);
    const float fw = wr ? fcW[u] : 0.0f;
    const float fb = fcB[0];
    float* ob = out + (size_t)b * TGT;

    x = 0.0f;                            // decoder_input = zeros
    for (int t = 0; t < TGT; ++t) {
        STEP(x)
        // fc partial: only qi==0 of active quads contributes fcW[u]*h[u]
        float p = wr ? fw * hn : 0.0f;
        p += dpp_perm<XOR1>(p);
        p += dpp_perm<XOR2>(p);
        p += __shfl_xor(p, 4, 64);
        p += __shfl_xor(p, 8, 64);
        p += __shfl_xor(p, 16, 64);
        p += __shfl_xor(p, 32, 64);
        if (lane == 0) pbuf[cur][w] = p;
        __syncthreads();                 // h + pbuf visible
        float4 pv = *(const float4*)pbuf[cur];
        float y = pv.x + pv.y + pv.z + pv.w + fb;  // all lanes have y
        if (tid == 0) ob[t] = y;
        cur ^= 1;
        x = y;                           // feed back as next input
    }
}

extern "C" void kernel_launch(void* const* d_in, const int* in_sizes, int n_in,
                              void* d_out, int out_size, void* d_ws, size_t ws_size,
                              hipStream_t stream) {
    const float* src  = (const float*)d_in[0];
    const float* eWih = (const float*)d_in[1];
    const float* eWhh = (const float*)d_in[2];
    const float* eBih = (const float*)d_in[3];
    const float* eBhh = (const float*)d_in[4];
    const float* dWih = (const float*)d_in[5];
    const float* dWhh = (const float*)d_in[6];
    const float* dBih = (const float*)d_in[7];
    const float* dBhh = (const float*)d_in[8];
    const float* fcW  = (const float*)d_in[9];
    const float* fcB  = (const float*)d_in[10];
    float* out = (float*)d_out;

    const int B = in_sizes[0] / SEQ;     // 2048
    seq2seq_kernel<<<B, 256, 0, stream>>>(src, eWih, eWhh, eBih, eBhh,
                                          dWih, dWhh, dBih, dBhh, fcW, fcB, out);
}

// Round 6
// 844.611 us; speedup vs baseline: 1.4101x; 1.2771x over previous
//
#include <hip/hip_runtime.h>

// Seq2Seq LSTM (enc 512 + dec 256 steps), H=50, B=2048, in/out dim 1.
//
// Round-6 = round-5 quad decomposition (block 256 = 1 element; quad Q owns
// unit u; lane qi=2*gp+kh handles gate-pair gp over k-half kh) with the
// issue-count fat removed:
//  * Weights PINNED into arch VGPRs via asm("" : "+v") -- r1-r5 all showed
//    VGPR_Count < live weight floats (compiler parks long-lived arrays in
//    AGPRs / remats them; each use then costs an extra VALU op).
//  * v_rcp_f32 via __builtin_amdgcn_rcpf (no fast-math => 1/x was the full
//    IEEE divide expansion, ~25 cyc, twice per step).
//  * Weight ordering: accum A = MY gate (qi), accum B = partner gate
//    (qi^1), so the k-half combine is a = (A) + dpp_xor1(B) -- no selects.
//  * c/hn computed validly only on lane qi==0 via 3 quad_perm gathers
//    (f=xor1, g=xor2, o=xor3); other lanes produce bounded garbage that is
//    never read (h-write & fc are wr-guarded; exp->Inf => rcp->0, no NaN).
//  * Gate-g beta=2 folded into its weights/bias; bias + wx*x folded into
//    accumulator init; 2x static unroll kills double-buffer index selects.

#define HID 50
#define SEQ 512
#define TGT 256
#define KH  28      // padded k-half (k-half 1 holds 22 real + 6 zeros)

#define XOR1 0xB1   // quad_perm [1,0,3,2]
#define XOR2 0x4E   // quad_perm [2,3,0,1]
#define XOR3 0x1B   // quad_perm [3,2,1,0]

template <int CTRL>
__device__ __forceinline__ float dppf(float x) {
    return __int_as_float(__builtin_amdgcn_update_dpp(
        0, __float_as_int(x), CTRL, 0xF, 0xF, true));
}

#define PIN(v) asm volatile("" : "+v"(v))

// Load my-gate row (wm, scaled sm) and partner-gate row (wq, scaled sq) over
// my k-slice [k0,k0+28), zero-padded past HID; wx/bb for MY gate, scaled sm.
#define LOAD_W(Wih, Whh, Bih, Bhh)                                     \
    {                                                                  \
        const int gmine = qi;                                          \
        const int gpart = qi ^ 1;                                      \
        const float* rm_ = (Whh) + (size_t)(gmine * HID + u) * HID;    \
        const float* rq_ = (Whh) + (size_t)(gpart * HID + u) * HID;    \
        _Pragma("unroll")                                              \
        for (int k = 0; k < KH; ++k) {                                 \
            int kk = k0 + k;                                           \
            wm[k] = (kk < HID) ? rm_[kk] * sm : 0.0f;                  \
            wq[k] = (kk < HID) ? rq_[kk] * sq : 0.0f;                  \
        }                                                              \
        wx = (Wih)[gmine * HID + u] * sm;                              \
        bb = ((Bih)[gmine * HID + u] + (Bhh)[gmine * HID + u]) * sm;   \
        _Pragma("unroll")                                              \
        for (int k = 0; k < KH; ++k) { PIN(wm[k]); PIN(wq[k]); }       \
        PIN(wx); PIN(bb);                                              \
    }

// One LSTM step: defines hn (valid on qi==0 lanes), updates c (ditto),
// writes new h into hOut (wr lanes). No barrier inside.
#define STEP(xv, hIn, hOut)                                            \
    float hn;                                                          \
    {                                                                  \
        const float4* h4_ = (const float4*)((hIn) + k0);               \
        float4 q0_ = h4_[0], q1_ = h4_[1], q2_ = h4_[2], q3_ = h4_[3], \
               q4_ = h4_[4], q5_ = h4_[5], q6_ = h4_[6];               \
        float hv_[KH] = {q0_.x,q0_.y,q0_.z,q0_.w, q1_.x,q1_.y,q1_.z,q1_.w, \
                         q2_.x,q2_.y,q2_.z,q2_.w, q3_.x,q3_.y,q3_.z,q3_.w, \
                         q4_.x,q4_.y,q4_.z,q4_.w, q5_.x,q5_.y,q5_.z,q5_.w, \
                         q6_.x,q6_.y,q6_.z,q6_.w};                     \
        float A0 = fmaf(wx, (xv), bb), A1 = 0.0f, B0 = 0.0f, B1 = 0.0f; \
        _Pragma("unroll")                                              \
        for (int k = 0; k < KH; k += 2) {                              \
            A0 = fmaf(wm[k],     hv_[k],     A0);                      \
            B0 = fmaf(wq[k],     hv_[k],     B0);                      \
            A1 = fmaf(wm[k + 1], hv_[k + 1], A1);                      \
            B1 = fmaf(wq[k + 1], hv_[k + 1], B1);                      \
        }                                                              \
        float apart = B0 + B1;                                         \
        float a = (A0 + A1) + dppf<XOR1>(apart);   /* my gate, full dot */ \
        float s_ = __builtin_amdgcn_rcpf(1.0f + __expf(-a));           \
        float act = fmaf(alpha, s_, gam);          /* sigm / tanh(g) */ \
        float f_ = dppf<XOR1>(act);                                    \
        float g_ = dppf<XOR2>(act);                                    \
        float o_ = dppf<XOR3>(act);                                    \
        c = fmaf(f_, c, act * g_);                 /* valid on qi==0 */ \
        float th = fmaf(2.0f,                                          \
            __builtin_amdgcn_rcpf(1.0f + __expf(-2.0f * c)), -1.0f);   \
        hn = o_ * th;                                                  \
        if (wr) (hOut)[Q] = hn;                                        \
    }

// Decoder step: STEP + fc reduction + y broadcast + feedback.
#define DSTEP(hIn, hOut, pb, tIdx)                                     \
    {                                                                  \
        STEP(x, hIn, hOut)                                             \
        float hs = wr ? hn : 0.0f;       /* kill garbage-lane values */ \
        float p = fw * hs;                                             \
        p += dppf<XOR1>(p);                                            \
        p += dppf<XOR2>(p);                                            \
        p += __shfl_xor(p, 4, 64);                                     \
        p += __shfl_xor(p, 8, 64);                                     \
        p += __shfl_xor(p, 16, 64);                                    \
        p += __shfl_xor(p, 32, 64);                                    \
        if (lane == 0) (pb)[w] = p;                                    \
        __syncthreads();                 /* pbuf + hOut visible */     \
        float4 pv_ = *(const float4*)(pb);                             \
        float y = pv_.x + pv_.y + pv_.z + pv_.w + fb;                  \
        if (tid == 0) ob[tIdx] = y;                                    \
        x = y;                                                         \
    }

extern "C" __global__ void __launch_bounds__(256, 2)
seq2seq_kernel(const float* __restrict__ src,
               const float* __restrict__ eWih, const float* __restrict__ eWhh,
               const float* __restrict__ eBih, const float* __restrict__ eBhh,
               const float* __restrict__ dWih, const float* __restrict__ dWhh,
               const float* __restrict__ dBih, const float* __restrict__ dBhh,
               const float* __restrict__ fcW, const float* __restrict__ fcB,
               float* __restrict__ out) {
    const int b    = blockIdx.x;
    const int tid  = threadIdx.x;        // 0..255
    const int lane = tid & 63;
    const int w    = tid >> 6;           // wave 0..3
    const int Q    = tid >> 2;           // quad id = unit id
    const int qi   = tid & 3;            // my gate (i,f,g,o)
    const int kh   = qi & 1;             // k-half
    const int k0   = kh * KH;            // 0 or 28 (112 B, 16B-aligned)
    const bool actQ = (Q < HID);
    const int u    = actQ ? Q : (HID - 1);
    const bool wr  = (qi == 0) && actQ;  // h writer / fc contributor

    __shared__ __align__(16) float hA[64], hB[64];   // static double buffer
    __shared__ __align__(16) float pA[4], pB[4];     // decoder fc partials

    if (tid < 64) { hA[tid] = 0.0f; hB[tid] = 0.0f; }
    __syncthreads();

    // unified activation: act = alpha*sigm(a') + gam, a' = beta*a with beta
    // folded into the weights (beta=2 for gate g -> tanh).
    const float alpha = (qi == 2) ? 2.0f : 1.0f;
    const float gam   = (qi == 2) ? -1.0f : 0.0f;
    const float sm    = (qi == 2) ? 2.0f : 1.0f;   // my-gate scale
    const float sq    = (qi == 3) ? 2.0f : 1.0f;   // partner-gate scale

    float wm[KH], wq[KH], wx, bb;
    float c = 0.0f;

    // ---------------- encoder: 512 steps (unrolled x2) ----------------
    LOAD_W(eWih, eWhh, eBih, eBhh);
    const float* sb = src + (size_t)b * SEQ;
    float* ob = out + (size_t)b * TGT;

    float x = sb[0];
    for (int t = 0; t < SEQ; t += 2) {
        float x1 = sb[t + 1];                       // prefetch
        float x2 = (t + 2 < SEQ) ? sb[t + 2] : 0.0f;
        { STEP(x, hA, hB) }
        __syncthreads();
        { STEP(x1, hB, hA) }
        __syncthreads();
        x = x2;
    }
    // state now in hA; lane-qi==0 c carries encoder final cell state

    // ---------------- decoder: 256 steps (unrolled x2) ----------------
    LOAD_W(dWih, dWhh, dBih, dBhh);
    const float fw = wr ? fcW[u] : 0.0f;
    const float fb = fcB[0];

    x = 0.0f;                                       // decoder_input = zeros
    for (int t = 0; t < TGT; t += 2) {
        DSTEP(hA, hB, pA, t)
        DSTEP(hB, hA, pB, t + 1)
    }
}

extern "C" void kernel_launch(void* const* d_in, const int* in_sizes, int n_in,
                              void* d_out, int out_size, void* d_ws, size_t ws_size,
                              hipStream_t stream) {
    const float* src  = (const float*)d_in[0];
    const float* eWih = (const float*)d_in[1];
    const float* eWhh = (const float*)d_in[2];
    const float* eBih = (const float*)d_in[3];
    const float* eBhh = (const float*)d_in[4];
    const float* dWih = (const float*)d_in[5];
    const float* dWhh = (const float*)d_in[6];
    const float* dBih = (const float*)d_in[7];
    const float* dBhh = (const float*)d_in[8];
    const float* fcW  = (const float*)d_in[9];
    const float* fcB  = (const float*)d_in[10];
    float* out = (float*)d_out;

    const int B = in_sizes[0] / SEQ;     // 2048
    seq2seq_kernel<<<B, 256, 0, stream>>>(src, eWih, eWhh, eBih, eBhh,
                                          dWih, dWhh, dBih, dBhh, fcW, fcB, out);
}

// Round 8
// 653.065 us; speedup vs baseline: 1.8237x; 1.2933x over previous
//
#include <hip/hip_runtime.h>

// Seq2Seq LSTM (enc 512 + dec 256 steps), H=50, B=2048, in/out dim 1.
//
// Round-8 = round-7 with the decoder scoping bug fixed (hn was declared
// inside an inner block; now each STEP and its consumer share one scope).
//
// Design (r7): 1 wave = 1 element (lane j owns unit j; lowest LDS delivery:
// 64 lanes x 50 h floats/step). The register-allocator fight is won AT THE
// USES: every weight multiply is an inline-asm v_pk_fma_f32 whose "v"
// constraints force the weight virtual registers into the arch-VGPR class.
// Rounds 1-6 all showed the compiler parking long-lived weight arrays in
// AGPRs (VGPR_Count 44-144 << live floats) and paying v_accvgpr_read per
// use; PIN-at-def (r6) did not stop it. ~240 live regs fits the 256 arch
// cap; __launch_bounds__(64,2) targets 2 waves/SIMD -- the whole 2048-block
// grid resident at once.
//
// Step: 13 broadcast ds_read_b128 of h (conflict-free), 100 asm pk_fma into
// 4 packed gate accumulators, rcp-based sigmoid/tanh, h write + 1 barrier
// (double-buffered LDS h). Decoder y via 6-shfl butterfly, fed back as x.

#define HID 50
#define SEQ 512
#define TGT 256

typedef float v2f __attribute__((ext_vector_type(2)));

// Packed FMA with arch-VGPR-forcing constraints: acc += w * h (2 floats).
#define PKFMA(acc, w, h) \
    asm("v_pk_fma_f32 %0, %1, %2, %0" : "+v"(acc) : "v"(w), "v"(h))

__device__ __forceinline__ float sigm(float x) {
    return __builtin_amdgcn_rcpf(1.0f + __expf(-x));      // inf-safe
}
__device__ __forceinline__ float tanh_(float x) {
    return fmaf(2.0f, __builtin_amdgcn_rcpf(1.0f + __expf(-2.0f * x)), -1.0f);
}

// Load this lane's 4 gate rows of W_hh as 25 v2f each (+ wx, summed bias).
// Row byte offset (g*50+u)*200 is 8B-aligned -> v2f loads legal.
#define LOAD_W(Wih, Whh, Bih, Bhh)                                    \
    {                                                                 \
        _Pragma("unroll")                                             \
        for (int g = 0; g < 4; ++g) {                                 \
            const v2f* r2 = (const v2f*)((Whh) + (size_t)(g * HID + u) * HID); \
            _Pragma("unroll")                                         \
            for (int p = 0; p < 25; ++p) wg[g][p] = r2[p];            \
            wx[g] = (Wih)[g * HID + u];                               \
            bb[g] = (Bih)[g * HID + u] + (Bhh)[g * HID + u];          \
        }                                                             \
    }

// One LSTM step. h read from hIn (52 floats, pads zero), result written to
// hOut; defines hn; updates c. No barrier inside. Caller provides scope.
#define STEP(xv, hIn, hOut)                                           \
    float hn;                                                         \
    {                                                                 \
        const float4* h4_ = (const float4*)(hIn);                     \
        v2f a0 = {bb[0], wx[0] * (xv)};                               \
        v2f a1 = {bb[1], wx[1] * (xv)};                               \
        v2f a2 = {bb[2], wx[2] * (xv)};                               \
        v2f a3 = {bb[3], wx[3] * (xv)};                               \
        _Pragma("unroll")                                             \
        for (int q = 0; q < 12; ++q) {                                \
            float4 hv = h4_[q];                                       \
            v2f hA = {hv.x, hv.y};                                    \
            v2f hB = {hv.z, hv.w};                                    \
            PKFMA(a0, wg[0][2 * q], hA);                              \
            PKFMA(a1, wg[1][2 * q], hA);                              \
            PKFMA(a2, wg[2][2 * q], hA);                              \
            PKFMA(a3, wg[3][2 * q], hA);                              \
            PKFMA(a0, wg[0][2 * q + 1], hB);                          \
            PKFMA(a1, wg[1][2 * q + 1], hB);                          \
            PKFMA(a2, wg[2][2 * q + 1], hB);                          \
            PKFMA(a3, wg[3][2 * q + 1], hB);                          \
        }                                                             \
        {   /* pair 24: k = 48,49 (h4_[12].xy real, .zw = pad) */     \
            float4 hv = h4_[12];                                      \
            v2f hA = {hv.x, hv.y};                                    \
            PKFMA(a0, wg[0][24], hA);                                 \
            PKFMA(a1, wg[1][24], hA);                                 \
            PKFMA(a2, wg[2][24], hA);                                 \
            PKFMA(a3, wg[3][24], hA);                                 \
        }                                                             \
        float gi = sigm(a0.x + a0.y);                                 \
        float gf = sigm(a1.x + a1.y);                                 \
        float gg = tanh_(a2.x + a2.y);                                \
        float go = sigm(a3.x + a3.y);                                 \
        c = fmaf(gf, c, gi * gg);                                     \
        hn = go * tanh_(c);                                           \
        if (act) (hOut)[j] = hn;   /* pads [50..51] stay 0 */         \
    }

extern "C" __global__ void __launch_bounds__(64, 2)
seq2seq_kernel(const float* __restrict__ src,
               const float* __restrict__ eWih, const float* __restrict__ eWhh,
               const float* __restrict__ eBih, const float* __restrict__ eBhh,
               const float* __restrict__ dWih, const float* __restrict__ dWhh,
               const float* __restrict__ dBih, const float* __restrict__ dBhh,
               const float* __restrict__ fcW, const float* __restrict__ fcB,
               float* __restrict__ out) {
    const int b = blockIdx.x;
    const int j = threadIdx.x;                  // lane 0..63
    const bool act = (j < HID);
    const int u = act ? j : (HID - 1);          // clamped unit id

    __shared__ __align__(16) float hA[52], hB[52];  // padded h, dbl-buffered
    if (j < 52) { hA[j] = 0.0f; hB[j] = 0.0f; }
    __syncthreads();

    v2f wg[4][25];                              // 200 weight VGPRs
    float wx[4], bb[4];
    float c = 0.0f;

    // ---------------- encoder: 512 steps (unrolled x2) ----------------
    LOAD_W(eWih, eWhh, eBih, eBhh);
    const float* sb = src + (size_t)b * SEQ;
    float x = sb[0];
    for (int t = 0; t < SEQ; t += 2) {
        float x1 = sb[t + 1];                            // prefetch
        float x2 = (t + 2 < SEQ) ? sb[t + 2] : 0.0f;
        { STEP(x, hA, hB) }
        __syncthreads();
        { STEP(x1, hB, hA) }
        __syncthreads();
        x = x2;
    }
    // state now in hA

    // ---------------- decoder: 256 steps (unrolled x2) ----------------
    LOAD_W(dWih, dWhh, dBih, dBhh);
    const float fw = act ? fcW[u] : 0.0f;       // lanes 50-63 contribute 0
    const float fb = fcB[0];
    float* ob = out + (size_t)b * TGT;

    x = 0.0f;                                   // decoder_input = zeros
    for (int t = 0; t < TGT; t += 2) {
        {
            STEP(x, hA, hB)
            float p = fw * hn;
#pragma unroll
            for (int off = 32; off > 0; off >>= 1) p += __shfl_xor(p, off, 64);
            float y = p + fb;                   // every lane has y
            if (j == 0) ob[t] = y;
            x = y;
        }
        __syncthreads();
        {
            STEP(x, hB, hA)
            float p = fw * hn;
#pragma unroll
            for (int off = 32; off > 0; off >>= 1) p += __shfl_xor(p, off, 64);
            float y = p + fb;
            if (j == 0) ob[t + 1] = y;
            x = y;
        }
        __syncthreads();
    }
}

extern "C" void kernel_launch(void* const* d_in, const int* in_sizes, int n_in,
                              void* d_out, int out_size, void* d_ws, size_t ws_size,
                              hipStream_t stream) {
    const float* src  = (const float*)d_in[0];
    const float* eWih = (const float*)d_in[1];
    const float* eWhh = (const float*)d_in[2];
    const float* eBih = (const float*)d_in[3];
    const float* eBhh = (const float*)d_in[4];
    const float* dWih = (const float*)d_in[5];
    const float* dWhh = (const float*)d_in[6];
    const float* dBih = (const float*)d_in[7];
    const float* dBhh = (const float*)d_in[8];
    const float* fcW  = (const float*)d_in[9];
    const float* fcB  = (const float*)d_in[10];
    float* out = (float*)d_out;

    const int B = in_sizes[0] / SEQ;            // 2048
    seq2seq_kernel<<<B, 64, 0, stream>>>(src, eWih, eWhh, eBih, eBhh,
                                         dWih, dWhh, dBih, dBhh, fcW, fcB, out);
}